// Round 18
// baseline (84.743 us; speedup 1.0000x reference)
//
#include <hip/hip_runtime.h>
#include <hip/hip_bf16.h>

#define B_ 8
#define C_ 64
#define OUT_ 64
#define KS_ 16
#define NS_ 4096
#define K_ 32
#define G_ 16   // support points (n) per block

typedef short bf16x8 __attribute__((ext_vector_type(8)));
typedef short short4v __attribute__((ext_vector_type(4)));
typedef float f32x4 __attribute__((ext_vector_type(4)));
typedef float f32x2 __attribute__((ext_vector_type(2)));

__device__ inline short f2bf(float f) {
    union { __hip_bfloat16 h; short s; } u;
    u.h = __float2bfloat16(f);
    return u.s;
}

__device__ inline f32x2 relu2(f32x2 v) {
    v.x = fmaxf(v.x, 0.f);
    v.y = fmaxf(v.y, 0.f);
    return v;
}

// s_F swizzle: read-spread by row bits (>>11), write-spread by m bits (>>7).
__device__ inline int swz2(int byte) {
    return byte ^ ((((byte >> 11) ^ (byte >> 7)) & 7) << 4);
}

// s_F base for local row nl = 4*w + i. Rows i=0,1 reuse the wave's own (dead)
// s_mat slot; rows i=2,3 use the exclusive upper 16KB. No cross-wave overlap
// until the single pre-phase-D barrier.
__device__ inline int fbase(int nl) {
    return (((nl >> 1) & 1) << 14) | ((nl >> 2) << 12) | ((nl & 1) << 11);
}

// one-time setup: blocks 0-255 build Wt2 bf16 [64][1024] with K-permutation
// j' = m*64 + c  (value = weight[c*16+m][o]); block 256 collapses layer 1.
__global__ __launch_bounds__(256) void setup_kernel(
    const float* __restrict__ w, short* __restrict__ wt,
    const float* __restrict__ W1, const float* __restrict__ b1,
    const float* __restrict__ centers, float* __restrict__ w1c) {
    int bid = blockIdx.x;
    if (bid < 256) {
        int idx = bid * 256 + threadIdx.x;   // 65536 total
        int row = idx >> 6, o = idx & 63;    // row = c*16+m
        int jp = (row & 15) * 64 + (row >> 4);   // j' = m*64 + c
        wt[o * 1024 + jp] = f2bf(w[idx]);
    } else {
        int i = threadIdx.x;
        if (i < 16) {
            float s0 = 0.f, s1 = 0.f, s2 = 0.f, c = b1[i];
            for (int s = 0; s < 16; ++s) {
                s0 += W1[i * 48 + s];
                s1 += W1[i * 48 + 16 + s];
                s2 += W1[i * 48 + 32 + s];
            }
            for (int j = 0; j < 48; ++j) c -= W1[i * 48 + j] * centers[j];
            ((float4*)w1c)[i] = make_float4(s0, s1, s2, c);
        }
    }
}

__global__ __launch_bounds__(256, 4) void convpoint_kernel(
    const float* __restrict__ input,      // (B,C,NS,K)
    const float* __restrict__ points,     // (B,3,NS,K)
    const float* __restrict__ support,    // (B,3,NS)
    const short* __restrict__ Wt,         // (OUT,1024) bf16, j'-permuted weight
    const float* __restrict__ W1c,        // (16,4) collapsed layer-1
    const float* __restrict__ bias,       // (OUT)
    const float* __restrict__ W2, const float* __restrict__ b2,
    const float* __restrict__ W3, const float* __restrict__ b3,
    float* __restrict__ out0,             // (B,OUT,NS)
    float* __restrict__ out1)             // (B,3,NS)
{
    __shared__ __align__(16) short s_buf[G_ * 1024];

    const int tid = threadIdx.x;
    const int bidx = blockIdx.x;
    const int b = bidx / (NS_ / G_);
    const int n0 = (bidx % (NS_ / G_)) * G_;

    const int wave = tid >> 6;
    const int lane = tid & 63;
    const int half = lane >> 5;
    const int kl = lane & 31;
    const int m15 = lane & 15;
    const int kc = lane >> 4;

    const float* inpB = input + (size_t)b * C_ * NS_ * K_;

    auto load_group = [&](float4 (&dst)[4][2], int nl) {
        #pragma unroll
        for (int ct = 0; ct < 4; ++ct) {
            const float* ap = inpB + ((size_t)(ct * 16 + m15) * NS_ + n0 + nl) * K_ + kc * 8;
            dst[ct][0] = *(const float4*)(ap);
            dst[ct][1] = *(const float4*)(ap + 4);
        }
    };

    // ---- entry prefetch: i=0 group issued BEFORE phase B (hidden under MLP) ----
    float4 pA[4][2], pB[4][2];
    load_group(pA, wave * 4 + 0);
    __builtin_amdgcn_sched_barrier(0);   // pin loads above phase B

    // ---- output 1: pass-through support_points (independent) ----
    if (tid < 3 * G_) {
        int d = tid >> 4, g = tid & 15;
        int idx = (b * 3 + d) * NS_ + n0 + g;
        out1[idx] = support[idx];
    }

    // ---- Phase A+B: normalize + collapsed 3-layer MLP, 2 points packed f32x2 ----
    // WAVE-LOCAL n-assignment: wave w computes nl = {4w..4w+3}
    {
        const int nla = 4 * wave + half;       // pi=0
        const int nlb = nla + 2;               // pi=1
        const int na = n0 + nla, nb = n0 + nlb;
        f32x2 p[3];
        f32x2 r2 = {0.f, 0.f};
        #pragma unroll
        for (int d = 0; d < 3; ++d) {
            const float* pp = points + (size_t)(b * 3 + d) * NS_ * K_;
            const float* sp = support + (b * 3 + d) * NS_;
            p[d].x = pp[(size_t)na * K_ + kl] - sp[na];
            p[d].y = pp[(size_t)nb * K_ + kl] - sp[nb];
            r2 += p[d] * p[d];
        }
        float r2a = r2.x, r2b = r2.y;
        #pragma unroll
        for (int m2 = 1; m2 < 32; m2 <<= 1) {
            r2a = fmaxf(r2a, __shfl_xor(r2a, m2, 64));
            r2b = fmaxf(r2b, __shfl_xor(r2b, m2, 64));
        }
        float ma = sqrtf(r2a), mb = sqrtf(r2b);
        f32x2 inv;
        inv.x = (ma == 0.f) ? 1.f : 1.f / ma;
        inv.y = (mb == 0.f) ? 1.f : 1.f / mb;
        #pragma unroll
        for (int d = 0; d < 3; ++d) p[d] *= inv;

        f32x2 h1[16];
        #pragma unroll
        for (int i = 0; i < 16; ++i) {
            float4 w = ((const float4*)W1c)[i];          // uniform -> SGPR
            f32x2 a = p[0] * w.x + p[1] * w.y + p[2] * w.z + w.w;
            h1[i] = relu2(a);
        }
        f32x2 h2[16];
        #pragma unroll
        for (int i = 0; i < 16; ++i) {
            f32x2 a = b2[i];
            #pragma unroll
            for (int j = 0; j < 16; ++j)
                a += h1[j] * W2[i * 16 + j];             // uniform -> SGPR, v_pk_fma
            h2[i] = relu2(a);
        }
        #pragma unroll
        for (int i = 0; i < 16; ++i) {
            f32x2 a = b3[i];
            #pragma unroll
            for (int j = 0; j < 16; ++j)
                a += h2[j] * W3[i * 16 + j];
            a = relu2(a);
            int offa = nla * 1024 + i * 64 + kl * 2;     // wave-own slot
            int offb = nlb * 1024 + i * 64 + kl * 2;
            *(short*)((char*)s_buf + (offa ^ ((i & 7) << 4))) = f2bf(a.x);
            *(short*)((char*)s_buf + (offb ^ ((i & 7) << 4))) = f2bf(a.y);
        }
    }
    // no barrier: wave reads back only its own s_mat slot

    // ---- hoist B-frags (own s_mat slot) to registers ----
    bf16x8 bfrag[4];
    #pragma unroll
    for (int i = 0; i < 4; ++i) {
        const int nl = wave * 4 + i;
        int boff = nl * 1024 + m15 * 64 + kc * 16;
        bfrag[i] = *(const bf16x8*)((const char*)s_buf + (boff ^ ((m15 & 7) << 4)));
    }
    // no barrier: phase-C writes land only in wave-private regions (fbase)

    // phase-C compute helper: cvt + MFMA + packed 8B LDS write (i literal)
    auto compute_iter = [&](const float4 (&src)[4][2], int i) {
        const int nl = wave * 4 + i;
        __builtin_amdgcn_s_setprio(1);           // T5: favor MFMA-entering wave
        #pragma unroll
        for (int ct = 0; ct < 4; ++ct) {
            bf16x8 afrag;
            #pragma unroll
            for (int e = 0; e < 4; ++e) {
                afrag[e]     = f2bf(((const float*)&src[ct][0])[e]);
                afrag[4 + e] = f2bf(((const float*)&src[ct][1])[e]);
            }
            f32x4 acc = {0.f, 0.f, 0.f, 0.f};
            acc = __builtin_amdgcn_mfma_f32_16x16x32_bf16(afrag, bfrag[i], acc, 0, 0, 0);
            short4v pk;
            #pragma unroll
            for (int r = 0; r < 4; ++r) pk[r] = f2bf(acc[r]);
            int off8 = fbase(nl) + m15 * 128 + ct * 32 + kc * 8;   // bytes
            *(short4v*)((char*)s_buf + swz2(off8)) = pk;
        }
        __builtin_amdgcn_s_setprio(0);
    };

    // ---- Phase C (MFMA): two-bank rotation ----
    load_group(pB, wave * 4 + 1);
    compute_iter(pA, 0);
    load_group(pA, wave * 4 + 2);
    compute_iter(pB, 1);
    load_group(pB, wave * 4 + 3);
    compute_iter(pA, 2);
    compute_iter(pB, 3);
    __syncthreads();   // the ONE barrier: phase D reads all waves' s_F rows

    // ---- Phase D (MFMA): out[n][o] = (sum_j' F[n][j'] * Wt[o][j'])/32 + bias[o] ----
    {
        const int o = wave * 16 + m15;
        const int abase = fbase(m15);                    // row n = m15
        f32x4 acc0 = {0.f, 0.f, 0.f, 0.f};
        f32x4 acc1 = {0.f, 0.f, 0.f, 0.f};
        const short* wrow = Wt + o * 1024;
        __builtin_amdgcn_s_setprio(1);                   // T5
        #pragma unroll
        for (int ks = 0; ks < 32; ++ks) {
            const int j0 = kc * 8 + ks * 32;             // j'-index
            int aoff = abase + j0 * 2;                   // bytes
            bf16x8 af = *(const bf16x8*)((const char*)s_buf + swz2(aoff));
            bf16x8 bf = *(const bf16x8*)(wrow + j0);
            if (ks & 1) acc1 = __builtin_amdgcn_mfma_f32_16x16x32_bf16(af, bf, acc1, 0, 0, 0);
            else        acc0 = __builtin_amdgcn_mfma_f32_16x16x32_bf16(af, bf, acc0, 0, 0, 0);
        }
        __builtin_amdgcn_s_setprio(0);
        const float bo = bias[o];
        float4 ov;
        ov.x = (acc0[0] + acc1[0]) * (1.f / 32.f) + bo;
        ov.y = (acc0[1] + acc1[1]) * (1.f / 32.f) + bo;
        ov.z = (acc0[2] + acc1[2]) * (1.f / 32.f) + bo;
        ov.w = (acc0[3] + acc1[3]) * (1.f / 32.f) + bo;
        *(float4*)&out0[(size_t)(b * OUT_ + o) * NS_ + n0 + kc * 4] = ov;
    }
}

extern "C" void kernel_launch(void* const* d_in, const int* in_sizes, int n_in,
                              void* d_out, int out_size, void* d_ws, size_t ws_size,
                              hipStream_t stream) {
    const float* input   = (const float*)d_in[0];
    const float* points  = (const float*)d_in[1];
    const float* support = (const float*)d_in[2];
    const float* weight  = (const float*)d_in[3];
    const float* bias    = (const float*)d_in[4];
    const float* centers = (const float*)d_in[5];
    const float* W1 = (const float*)d_in[6];
    const float* b1 = (const float*)d_in[7];
    const float* W2 = (const float*)d_in[8];
    const float* b2 = (const float*)d_in[9];
    const float* W3 = (const float*)d_in[10];
    const float* b3 = (const float*)d_in[11];

    float* out0 = (float*)d_out;
    float* out1 = out0 + (size_t)B_ * OUT_ * NS_;

    short* wt  = (short*)d_ws;                       // 128 KB
    float* w1c = (float*)((char*)d_ws + 131072);     // 256 B
    setup_kernel<<<257, 256, 0, stream>>>(weight, wt, W1, b1, centers, w1c);

    dim3 grid(B_ * (NS_ / G_));
    convpoint_kernel<<<grid, 256, 0, stream>>>(
        input, points, support, wt, w1c, bias,
        W2, b2, W3, b3, out0, out1);
}

// Round 19
// 83.223 us; speedup vs baseline: 1.0183x; 1.0183x over previous
//
#include <hip/hip_runtime.h>
#include <hip/hip_bf16.h>

#define B_ 8
#define C_ 64
#define OUT_ 64
#define KS_ 16
#define NS_ 4096
#define K_ 32
#define G_ 16   // support points (n) per block

typedef short bf16x8 __attribute__((ext_vector_type(8)));
typedef short short4v __attribute__((ext_vector_type(4)));
typedef float f32x4 __attribute__((ext_vector_type(4)));
typedef float f32x2 __attribute__((ext_vector_type(2)));

__device__ inline short f2bf(float f) {
    union { __hip_bfloat16 h; short s; } u;
    u.h = __float2bfloat16(f);
    return u.s;
}

__device__ inline f32x2 relu2(f32x2 v) {
    v.x = fmaxf(v.x, 0.f);
    v.y = fmaxf(v.y, 0.f);
    return v;
}

// s_F swizzle: read-spread by row bits (>>11), write-spread by m bits (>>7).
// Pure function of byte offset, XORs bits 4-6 only -> 8B/16B runs preserved.
__device__ inline int swz2(int byte) {
    return byte ^ ((((byte >> 11) ^ (byte >> 7)) & 7) << 4);
}

// s_F base for local row nl = 4*w + i (w = wave). Rows i=0,1 reuse the wave's
// own (dead) s_mat slot [4096w, +4096); rows i=2,3 use exclusive upper 16KB.
// No cross-wave overlap until the single pre-phase-D barrier.
__device__ inline int fbase(int nl) {
    return (((nl >> 1) & 1) << 14) | ((nl >> 2) << 12) | ((nl & 1) << 11);
}

// one-time setup: blocks 0-255 build Wt2 bf16 [64][1024] with K-permutation
// j' = m*64 + c  (value = weight[c*16+m][o]); block 256 collapses layer 1.
__global__ __launch_bounds__(256) void setup_kernel(
    const float* __restrict__ w, short* __restrict__ wt,
    const float* __restrict__ W1, const float* __restrict__ b1,
    const float* __restrict__ centers, float* __restrict__ w1c) {
    int bid = blockIdx.x;
    if (bid < 256) {
        int idx = bid * 256 + threadIdx.x;   // 65536 total
        int row = idx >> 6, o = idx & 63;    // row = c*16+m
        int jp = (row & 15) * 64 + (row >> 4);   // j' = m*64 + c
        wt[o * 1024 + jp] = f2bf(w[idx]);
    } else {
        int i = threadIdx.x;
        if (i < 16) {
            float s0 = 0.f, s1 = 0.f, s2 = 0.f, c = b1[i];
            for (int s = 0; s < 16; ++s) {
                s0 += W1[i * 48 + s];
                s1 += W1[i * 48 + 16 + s];
                s2 += W1[i * 48 + 32 + s];
            }
            for (int j = 0; j < 48; ++j) c -= W1[i * 48 + j] * centers[j];
            ((float4*)w1c)[i] = make_float4(s0, s1, s2, c);
        }
    }
}

__global__ __launch_bounds__(256, 4) void convpoint_kernel(
    const float* __restrict__ input,      // (B,C,NS,K)
    const float* __restrict__ points,     // (B,3,NS,K)
    const float* __restrict__ support,    // (B,3,NS)
    const short* __restrict__ Wt,         // (OUT,1024) bf16, j'-permuted weight
    const float* __restrict__ W1c,        // (16,4) collapsed layer-1
    const float* __restrict__ bias,       // (OUT)
    const float* __restrict__ W2, const float* __restrict__ b2,
    const float* __restrict__ W3, const float* __restrict__ b3,
    float* __restrict__ out0,             // (B,OUT,NS)
    float* __restrict__ out1)             // (B,3,NS)
{
    // 32 KB buffer:
    //  - phase B:  s_mat [nl][m][k] bf16, off = nl*1024+m*64+k*2 ^ ((m&7)<<4)
    //              (wave w owns [4096w, 4096w+4096), first 16 KB only)
    //  - phase C/D: s_F rows at fbase(nl), within-row (m*64+c)*2, swz2 applied
    __shared__ __align__(16) short s_buf[G_ * 1024];

    const int tid = threadIdx.x;
    const int bidx = blockIdx.x;
    const int b = bidx / (NS_ / G_);
    const int n0 = (bidx % (NS_ / G_)) * G_;

    const int wave = tid >> 6;
    const int lane = tid & 63;
    const int half = lane >> 5;
    const int kl = lane & 31;
    const int m15 = lane & 15;
    const int kc = lane >> 4;

    const float* inpB = input + (size_t)b * C_ * NS_ * K_;

    // phase-C load helper: one iteration's A-operands (4 c-tiles, 32B/lane)
    auto load_group = [&](float4 (&dst)[4][2], int nl) {
        #pragma unroll
        for (int ct = 0; ct < 4; ++ct) {
            const float* ap = inpB + ((size_t)(ct * 16 + m15) * NS_ + n0 + nl) * K_ + kc * 8;
            dst[ct][0] = *(const float4*)(ap);
            dst[ct][1] = *(const float4*)(ap + 4);
        }
    };

    // ---- entry prefetch: i=0 group issued BEFORE phase B (hidden under MLP) ----
    float4 pA[4][2], pB[4][2];
    load_group(pA, wave * 4 + 0);
    __builtin_amdgcn_sched_barrier(0);   // pin loads above phase B

    // ---- output 1: pass-through support_points (independent) ----
    if (tid < 3 * G_) {
        int d = tid >> 4, g = tid & 15;
        int idx = (b * 3 + d) * NS_ + n0 + g;
        out1[idx] = support[idx];
    }

    // ---- Phase A+B: normalize + collapsed 3-layer MLP, 2 points packed f32x2 ----
    // WAVE-LOCAL n-assignment: wave w computes nl = {4w, 4w+1, 4w+2, 4w+3}
    // (lanes 0-31 -> nl=4w+0/ +2, lanes 32-63 -> nl=4w+1/ +3)
    {
        const int nla = 4 * wave + half;       // pi=0
        const int nlb = nla + 2;               // pi=1
        const int na = n0 + nla, nb = n0 + nlb;
        f32x2 p[3];
        f32x2 r2 = {0.f, 0.f};
        #pragma unroll
        for (int d = 0; d < 3; ++d) {
            const float* pp = points + (size_t)(b * 3 + d) * NS_ * K_;
            const float* sp = support + (b * 3 + d) * NS_;
            p[d].x = pp[(size_t)na * K_ + kl] - sp[na];
            p[d].y = pp[(size_t)nb * K_ + kl] - sp[nb];
            r2 += p[d] * p[d];
        }
        float r2a = r2.x, r2b = r2.y;
        #pragma unroll
        for (int m2 = 1; m2 < 32; m2 <<= 1) {   // reduce within 32-lane halves
            r2a = fmaxf(r2a, __shfl_xor(r2a, m2, 64));
            r2b = fmaxf(r2b, __shfl_xor(r2b, m2, 64));
        }
        float ma = sqrtf(r2a), mb = sqrtf(r2b);
        f32x2 inv;
        inv.x = (ma == 0.f) ? 1.f : 1.f / ma;
        inv.y = (mb == 0.f) ? 1.f : 1.f / mb;
        #pragma unroll
        for (int d = 0; d < 3; ++d) p[d] *= inv;

        f32x2 h1[16];
        #pragma unroll
        for (int i = 0; i < 16; ++i) {
            float4 w = ((const float4*)W1c)[i];          // uniform -> SGPR
            f32x2 a = p[0] * w.x + p[1] * w.y + p[2] * w.z + w.w;
            h1[i] = relu2(a);
        }
        f32x2 h2[16];
        #pragma unroll
        for (int i = 0; i < 16; ++i) {
            f32x2 a = b2[i];
            #pragma unroll
            for (int j = 0; j < 16; ++j)
                a += h1[j] * W2[i * 16 + j];             // uniform -> SGPR, v_pk_fma
            h2[i] = relu2(a);
        }
        #pragma unroll
        for (int i = 0; i < 16; ++i) {
            f32x2 a = b3[i];
            #pragma unroll
            for (int j = 0; j < 16; ++j)
                a += h2[j] * W3[i * 16 + j];
            a = relu2(a);
            int offa = nla * 1024 + i * 64 + kl * 2;     // wave-own slot
            int offb = nlb * 1024 + i * 64 + kl * 2;
            *(short*)((char*)s_buf + (offa ^ ((i & 7) << 4))) = f2bf(a.x);
            *(short*)((char*)s_buf + (offb ^ ((i & 7) << 4))) = f2bf(a.y);
        }
    }
    // NO __syncthreads: wave reads back only its own s_mat slot (in-order LDS
    // within a wave + compiler lgkmcnt).

    // ---- hoist B-frags (own s_mat slot) to registers ----
    bf16x8 bfrag[4];
    #pragma unroll
    for (int i = 0; i < 4; ++i) {
        const int nl = wave * 4 + i;
        int boff = nl * 1024 + m15 * 64 + kc * 16;
        bfrag[i] = *(const bf16x8*)((const char*)s_buf + (boff ^ ((m15 & 7) << 4)));
    }
    // NO __syncthreads: phase-C writes land only in the wave's own dead s_mat
    // slot + its exclusive upper region (fbase).

    // phase-C compute helper: cvt + MFMA + packed 8B LDS write (i literal)
    auto compute_iter = [&](const float4 (&src)[4][2], int i) {
        const int nl = wave * 4 + i;
        #pragma unroll
        for (int ct = 0; ct < 4; ++ct) {
            bf16x8 afrag;
            #pragma unroll
            for (int e = 0; e < 4; ++e) {
                afrag[e]     = f2bf(((const float*)&src[ct][0])[e]);
                afrag[4 + e] = f2bf(((const float*)&src[ct][1])[e]);
            }
            f32x4 acc = {0.f, 0.f, 0.f, 0.f};
            acc = __builtin_amdgcn_mfma_f32_16x16x32_bf16(afrag, bfrag[i], acc, 0, 0, 0);
            short4v pk;
            #pragma unroll
            for (int r = 0; r < 4; ++r) pk[r] = f2bf(acc[r]);
            int off8 = fbase(nl) + m15 * 128 + ct * 32 + kc * 8;   // bytes
            *(short4v*)((char*)s_buf + swz2(off8)) = pk;
        }
    };

    // ---- Phase C (MFMA): two-bank rotation — next group's loads fly over compute ----
    load_group(pB, wave * 4 + 1);
    compute_iter(pA, 0);
    load_group(pA, wave * 4 + 2);
    compute_iter(pB, 1);
    load_group(pB, wave * 4 + 3);
    compute_iter(pA, 2);
    compute_iter(pB, 3);
    __syncthreads();   // the ONE barrier: phase D reads all waves' s_F rows

    // ---- Phase D (MFMA): out[n][o] = (sum_j' F[n][j'] * Wt[o][j'])/32 + bias[o] ----
    // GEMM M=16(n) N=16(o per wave) K=1024, K-dim order j' = m*64+c
    {
        const int o = wave * 16 + m15;
        const int abase = fbase(m15);                    // row n = m15
        f32x4 acc0 = {0.f, 0.f, 0.f, 0.f};
        f32x4 acc1 = {0.f, 0.f, 0.f, 0.f};
        const short* wrow = Wt + o * 1024;
        #pragma unroll
        for (int ks = 0; ks < 32; ++ks) {
            const int j0 = kc * 8 + ks * 32;             // j'-index
            int aoff = abase + j0 * 2;                   // bytes
            bf16x8 af = *(const bf16x8*)((const char*)s_buf + swz2(aoff));
            bf16x8 bf = *(const bf16x8*)(wrow + j0);
            if (ks & 1) acc1 = __builtin_amdgcn_mfma_f32_16x16x32_bf16(af, bf, acc1, 0, 0, 0);
            else        acc0 = __builtin_amdgcn_mfma_f32_16x16x32_bf16(af, bf, acc0, 0, 0, 0);
        }
        const float bo = bias[o];
        float4 ov;
        ov.x = (acc0[0] + acc1[0]) * (1.f / 32.f) + bo;
        ov.y = (acc0[1] + acc1[1]) * (1.f / 32.f) + bo;
        ov.z = (acc0[2] + acc1[2]) * (1.f / 32.f) + bo;
        ov.w = (acc0[3] + acc1[3]) * (1.f / 32.f) + bo;
        // D rows: n = kc*4 + r (4 consecutive) at col o
        *(float4*)&out0[(size_t)(b * OUT_ + o) * NS_ + n0 + kc * 4] = ov;
    }
}

extern "C" void kernel_launch(void* const* d_in, const int* in_sizes, int n_in,
                              void* d_out, int out_size, void* d_ws, size_t ws_size,
                              hipStream_t stream) {
    const float* input   = (const float*)d_in[0];
    const float* points  = (const float*)d_in[1];
    const float* support = (const float*)d_in[2];
    const float* weight  = (const float*)d_in[3];
    const float* bias    = (const float*)d_in[4];
    const float* centers = (const float*)d_in[5];
    const float* W1 = (const float*)d_in[6];
    const float* b1 = (const float*)d_in[7];
    const float* W2 = (const float*)d_in[8];
    const float* b2 = (const float*)d_in[9];
    const float* W3 = (const float*)d_in[10];
    const float* b3 = (const float*)d_in[11];

    float* out0 = (float*)d_out;
    float* out1 = out0 + (size_t)B_ * OUT_ * NS_;

    short* wt  = (short*)d_ws;                       // 128 KB
    float* w1c = (float*)((char*)d_ws + 131072);     // 256 B
    setup_kernel<<<257, 256, 0, stream>>>(weight, wt, W1, b1, centers, w1c);

    dim3 grid(B_ * (NS_ / G_));
    convpoint_kernel<<<grid, 256, 0, stream>>>(
        input, points, support, wt, w1c, bias,
        W2, b2, W3, b3, out0, out1);
}